// Round 12
// baseline (629.404 us; speedup 1.0000x reference)
//
#include <hip/hip_runtime.h>

#define NN 50000
#define NE 800000
#define DD 256
#define NG 64
#define MPAD 50048  // 128 * 391

// counting-sort parameters
#define HC 64          // edge chunks (NE/HC = 12500)
#define EPC (NE / HC)  // 12500
#define HBINS 32768    // bins/part, u16-packed -> 64 KB LDS (2 parts)
#define FBINS 16384    // bins/part, u32 counters -> 64 KB LDS (4 parts)

// parallel scan
#define SB 196         // SB*256 = 50176 >= NN+1

// aggregation
#define TN 128         // rel packing block (dst & 127)
#define CH 4           // dsts per wave (128 % CH == 0 -> chunk never straddles a 128-block)

typedef __attribute__((ext_vector_type(8))) short bf16x8;
typedef __attribute__((ext_vector_type(4))) float f32x4;

__device__ __forceinline__ float bf2f(unsigned short u) {
  union { unsigned int i; float f; } v; v.i = ((unsigned int)u) << 16; return v.f;
}
__device__ __forceinline__ unsigned short f2bf(float f) {
  union { float f; unsigned int i; } v; v.f = f;
  unsigned int x = v.i;
  x += 0x7fffu + ((x >> 16) & 1u);  // RNE
  return (unsigned short)(x >> 16);
}
__device__ __forceinline__ float bflo(unsigned int w) {
  union { unsigned int i; float f; } v; v.i = w << 16; return v.f;
}
__device__ __forceinline__ float bfhi(unsigned int w) {
  union { unsigned int i; float f; } v; v.i = w & 0xffff0000u; return v.f;
}

// ---------------- init / casts ----------------
__global__ void k_zero(unsigned int* __restrict__ p, int n) {
  int i = blockIdx.x * blockDim.x + threadIdx.x;
  int st = gridDim.x * blockDim.x;
  for (; i < n; i += st) p[i] = 0u;
}

__global__ void k_castW(const float* __restrict__ W, unsigned short* __restrict__ Wt) {
  int i = blockIdx.x * blockDim.x + threadIdx.x;
  int n = i >> 8, k = i & 255;
  Wt[i] = f2bf(W[k * 256 + n]);
}

__global__ void k_castX(const float* __restrict__ x, unsigned short* __restrict__ xb) {
  int i = blockIdx.x * blockDim.x + threadIdx.x;
  int e = i * 4;
  int row = e >> 8;
  float4 v = make_float4(0.f, 0.f, 0.f, 0.f);
  if (row < NN) v = *(const float4*)(x + e);
  ushort4 u;
  u.x = f2bf(v.x); u.y = f2bf(v.y); u.z = f2bf(v.z); u.w = f2bf(v.w);
  *(ushort4*)(xb + e) = u;
}

// ---------------- GEMM: h1'[row][col] = dinv[row] * (A @ B), row-major ----------------
__global__ __launch_bounds__(256) void k_gemm(const unsigned short* __restrict__ A,
                                              const unsigned short* __restrict__ Bt,
                                              const float* __restrict__ dinv,
                                              unsigned short* __restrict__ C) {
  __shared__ unsigned short As[128][40];
  __shared__ unsigned short Bs[64][40];
  int tid = threadIdx.x;
  int lane = tid & 63;
  int wave = tid >> 6;
  int wm = wave >> 1, wn = wave & 1;
  int m0 = blockIdx.x * 128, n0 = blockIdx.y * 64;
  int l15 = lane & 15, l4 = lane >> 4;
  f32x4 acc[4][2] = {};

  for (int ks = 0; ks < 8; ++ks) {
    int k0 = ks * 32;
    {
      int c = tid, r = c >> 2, cc = c & 3;
      *(uint4*)(&As[r][cc * 8]) = *(const uint4*)(A + (size_t)(m0 + r) * 256 + k0 + cc * 8);
      c = tid + 256; r = c >> 2; cc = c & 3;
      *(uint4*)(&As[r][cc * 8]) = *(const uint4*)(A + (size_t)(m0 + r) * 256 + k0 + cc * 8);
      c = tid; r = c >> 2; cc = c & 3;
      *(uint4*)(&Bs[r][cc * 8]) = *(const uint4*)(Bt + (size_t)(n0 + r) * 256 + k0 + cc * 8);
    }
    __syncthreads();
    bf16x8 a[4], b[2];
#pragma unroll
    for (int fm = 0; fm < 4; ++fm)
      a[fm] = *(const bf16x8*)(&As[wm * 64 + fm * 16 + l15][l4 * 8]);
#pragma unroll
    for (int fn = 0; fn < 2; ++fn)
      b[fn] = *(const bf16x8*)(&Bs[wn * 32 + fn * 16 + l15][l4 * 8]);
#pragma unroll
    for (int fm = 0; fm < 4; ++fm)
#pragma unroll
      for (int fn = 0; fn < 2; ++fn)
        acc[fm][fn] = __builtin_amdgcn_mfma_f32_16x16x32_bf16(a[fm], b[fn], acc[fm][fn], 0, 0, 0);
    __syncthreads();
  }
  int r0 = l4 * 4;
#pragma unroll
  for (int fm = 0; fm < 4; ++fm)
#pragma unroll
    for (int fn = 0; fn < 2; ++fn) {
      int row = m0 + wm * 64 + fm * 16 + r0;
      int col = n0 + wn * 32 + fn * 16 + l15;
#pragma unroll
      for (int r = 0; r < 4; ++r) {
        int rr = row + r;
        float dv = dinv[rr < NN ? rr : 0];
        C[(size_t)rr * 256 + col] = f2bf(dv * acc[fm][fn][r]);
      }
    }
}

// ---------------- counting sort (by dst) ----------------
__global__ __launch_bounds__(256) void k_hist2(const int* __restrict__ key,
                                               unsigned int* __restrict__ partial) {
  __shared__ unsigned int lh[HBINS / 2];  // 64 KB u16-packed
  int tid = threadIdx.x;
  int c = blockIdx.x, p = blockIdx.y;
  for (int w = tid; w < HBINS / 2; w += 256) lh[w] = 0u;
  __syncthreads();
  int lo = c * EPC, hi = lo + EPC;
  int b0 = p * HBINS;
  for (int i = lo + tid; i < hi; i += 256) {
    int rel = key[i] - b0;
    if ((unsigned)rel < (unsigned)HBINS)
      atomicAdd(&lh[rel >> 1], 1u << ((rel & 1) * 16));
  }
  __syncthreads();
  int wbase = p * (HBINS / 2);
  for (int w = tid; w < HBINS / 2; w += 256) {
    int gw = wbase + w;
    if (gw < NN / 2) partial[(size_t)c * (NN / 2) + gw] = lh[w];
  }
}

// reduce partials -> deg AND dinv
__global__ void k_reduce(const unsigned int* __restrict__ partial, int* __restrict__ deg,
                         float* __restrict__ dinv) {
  int w = blockIdx.x * blockDim.x + threadIdx.x;
  if (w >= NN / 2) return;
  unsigned int sl = 0, sh = 0;
#pragma unroll
  for (int c = 0; c < HC; ++c) {
    unsigned int v = partial[(size_t)c * (NN / 2) + w];
    sl += v & 0xffffu;
    sh += v >> 16;
  }
  *(int2*)(deg + 2 * w) = make_int2((int)sl, (int)sh);
  dinv[2 * w] = rsqrtf((float)sl + 1.0f);
  dinv[2 * w + 1] = rsqrtf((float)sh + 1.0f);
}

// 3-dispatch parallel exclusive scan: deg[NN] -> rp[NN+1]
__global__ __launch_bounds__(256) void k_bsum(const int* __restrict__ deg, int* __restrict__ bsums) {
  __shared__ int s[256];
  int b = blockIdx.x, t = threadIdx.x, i = b * 256 + t;
  int v = (i < NN) ? deg[i] : 0;
  s[t] = v; __syncthreads();
  for (int off = 128; off > 0; off >>= 1) {
    if (t < off) s[t] += s[t + off];
    __syncthreads();
  }
  if (t == 0) bsums[b] = s[0];
}
__global__ __launch_bounds__(256) void k_sscan(int* __restrict__ bsums) {
  __shared__ int s[256];
  int t = threadIdx.x;
  int v = (t < SB) ? bsums[t] : 0;
  s[t] = v; __syncthreads();
  for (int off = 1; off < 256; off <<= 1) {
    int tmp = (t >= off) ? s[t - off] : 0;
    __syncthreads();
    s[t] += tmp;
    __syncthreads();
  }
  if (t < SB) bsums[t] = s[t] - v;  // exclusive
}
__global__ __launch_bounds__(256) void k_fillrp(const int* __restrict__ deg,
                                                const int* __restrict__ bsums,
                                                int* __restrict__ rp) {
  __shared__ int s[256];
  int b = blockIdx.x, t = threadIdx.x, i = b * 256 + t;
  int v = (i < NN) ? deg[i] : 0;
  s[t] = v; __syncthreads();
  for (int off = 1; off < 256; off <<= 1) {
    int tmp = (t >= off) ? s[t - off] : 0;
    __syncthreads();
    s[t] += tmp;
    __syncthreads();
  }
  int excl = bsums[b] + s[t] - v;
  if (i <= NN) rp[i] = excl;
}

// base[c][b] = rp[b] + sum_{c'<c} partial16[c'][b]
__global__ void k_base(const unsigned short* __restrict__ partial16,
                       const int* __restrict__ rp, int* __restrict__ base) {
  int b = blockIdx.x * blockDim.x + threadIdx.x;
  if (b >= NN) return;
  int run = rp[b];
#pragma unroll
  for (int c = 0; c < HC; ++c) {
    base[(size_t)c * NN + b] = run;
    run += (int)partial16[(size_t)c * NN + b];
  }
}

// graph boundaries from sorted batch
__global__ void k_bounds(const int* __restrict__ batch, int* __restrict__ starts) {
  int i = blockIdx.x * blockDim.x + threadIdx.x;
  if (i > NN) return;
  if (i == 0) {
    int b0 = batch[0];
    for (int g = 0; g <= b0; ++g) starts[g] = 0;
  } else if (i == NN) {
    int bl = batch[NN - 1];
    for (int g = bl + 1; g <= NG; ++g) starts[g] = NN;
  } else {
    int a = batch[i - 1], b = batch[i];
    for (int g = a + 1; g <= b; ++g) starts[g] = i;
  }
}

// in-CSR fill (keyed by dst): csr_pk = ((dst&127)<<16)|src
__global__ __launch_bounds__(256) void k_fill2(const int* __restrict__ src,
                                               const int* __restrict__ dst,
                                               const int* __restrict__ base,
                                               unsigned int* __restrict__ csr_pk) {
  __shared__ unsigned int pos[FBINS];  // 64 KB
  int tid = threadIdx.x;
  int c = blockIdx.x, p = blockIdx.y;
  int b0 = p * FBINS;
  for (int w = tid; w < FBINS; w += 256) {
    int gb = b0 + w;
    pos[w] = (gb < NN) ? (unsigned int)base[(size_t)c * NN + gb] : 0u;
  }
  __syncthreads();
  int lo = c * EPC, hi = lo + EPC;
  for (int i = lo + tid; i < hi; i += 256) {
    int d = dst[i];
    int s = src[i];
    int rel = d - b0;
    if ((unsigned)rel < (unsigned)FBINS) {
      int idx = (int)atomicAdd(&pos[rel], 1u);
      csr_pk[idx] = ((unsigned int)(d & (TN - 1)) << 16) | (unsigned int)s;
    }
  }
}

// ---------------- conv1: wave-per-CH-dsts, full 256-feature row per edge ----------------
// z' = dinv * elu(dinv*(sum h1'[src] + h1'[d]) + b1). No LDS, no atomics, no barriers.
// Run-detection flush is wave-uniform; deg-0 dsts handled by written-mask sweep.
// Next-batch csr_pk prefetch keeps the load off the shfl critical path.
__global__ __launch_bounds__(256) void k_agg1w(const unsigned short* __restrict__ h1,
                                               const unsigned int* __restrict__ csr_pk,
                                               const int* __restrict__ rp,
                                               const float* __restrict__ dinv,
                                               const float* __restrict__ b1,
                                               unsigned short* __restrict__ z) {
  int wid = blockIdx.x * 4 + (threadIdx.x >> 6);
  int lane = threadIdx.x & 63;
  int d0 = wid * CH;
  if (d0 >= NN) return;
  float4 b1v = *(const float4*)(b1 + lane * 4);
  int e0 = rp[d0], e1 = rp[d0 + CH];
  int base_d = d0 - (d0 & (TN - 1));
  float a0 = 0.f, a1 = 0.f, a2 = 0.f, a3 = 0.f;
  int cur = -1;
  unsigned int wmask = 0u;

  auto flushz = [&](int rel) {
    int d = base_d + rel;
    wmask |= 1u << (d - d0);
    float di = dinv[d];
    uint2 hv = *(const uint2*)(h1 + ((size_t)d << 8) + lane * 4);
    float u0 = di * (a0 + bflo(hv.x)) + b1v.x;
    float u1 = di * (a1 + bfhi(hv.x)) + b1v.y;
    float u2 = di * (a2 + bflo(hv.y)) + b1v.z;
    float u3 = di * (a3 + bfhi(hv.y)) + b1v.w;
    u0 = u0 > 0.f ? u0 : expm1f(u0);
    u1 = u1 > 0.f ? u1 : expm1f(u1);
    u2 = u2 > 0.f ? u2 : expm1f(u2);
    u3 = u3 > 0.f ? u3 : expm1f(u3);
    uint2 ow;
    ow.x = (unsigned int)f2bf(di * u0) | ((unsigned int)f2bf(di * u1) << 16);
    ow.y = (unsigned int)f2bf(di * u2) | ((unsigned int)f2bf(di * u3) << 16);
    *(uint2*)(z + ((size_t)d << 8) + lane * 4) = ow;
    a0 = a1 = a2 = a3 = 0.f;
  };

  unsigned int pk = 0u;
  if (e0 + lane < e1) pk = csr_pk[e0 + lane];
  for (int bb = e0; bb < e1; bb += 64) {
    int n = min(64, e1 - bb);
    unsigned int npk = 0u;
    if (bb + 64 + lane < e1) npk = csr_pk[bb + 64 + lane];
    for (int q = 0; q < n; q += 8) {
      int m = n - q; m = m > 8 ? 8 : m;
      unsigned int p[8]; uint2 vv[8];
      if (m == 8) {
#pragma unroll
        for (int t = 0; t < 8; ++t) p[t] = (unsigned int)__shfl((int)pk, q + t, 64);
#pragma unroll
        for (int t = 0; t < 8; ++t)
          vv[t] = *(const uint2*)(h1 + ((size_t)(p[t] & 0xffffu) << 8) + lane * 4);
#pragma unroll
        for (int t = 0; t < 8; ++t) {
          int rel = (int)(p[t] >> 16);
          if (rel != cur) { if (cur >= 0) flushz(cur); cur = rel; }
          a0 += bflo(vv[t].x); a1 += bfhi(vv[t].x);
          a2 += bflo(vv[t].y); a3 += bfhi(vv[t].y);
        }
      } else {
#pragma unroll
        for (int t = 0; t < 8; ++t) if (t < m)
          p[t] = (unsigned int)__shfl((int)pk, q + t, 64);
#pragma unroll
        for (int t = 0; t < 8; ++t) if (t < m)
          vv[t] = *(const uint2*)(h1 + ((size_t)(p[t] & 0xffffu) << 8) + lane * 4);
#pragma unroll
        for (int t = 0; t < 8; ++t) if (t < m) {
          int rel = (int)(p[t] >> 16);
          if (rel != cur) { if (cur >= 0) flushz(cur); cur = rel; }
          a0 += bflo(vv[t].x); a1 += bfhi(vv[t].x);
          a2 += bflo(vv[t].y); a3 += bfhi(vv[t].y);
        }
      }
    }
    pk = npk;
  }
  if (cur >= 0) flushz(cur);
#pragma unroll
  for (int j = 0; j < CH; ++j)
    if (!((wmask >> j) & 1u)) flushz((d0 & (TN - 1)) + j);
}

// ---------------- conv2+pool: same skeleton over z'; per-graph reg acc -> atomic pool ----
__global__ __launch_bounds__(256) void k_agg2w(const unsigned short* __restrict__ zz,
                                               const unsigned int* __restrict__ csr_pk,
                                               const int* __restrict__ rp,
                                               const float* __restrict__ dinv,
                                               const int* __restrict__ batch,
                                               float* __restrict__ pool) {
  int wid = blockIdx.x * 4 + (threadIdx.x >> 6);
  int lane = threadIdx.x & 63;
  int d0 = wid * CH;
  if (d0 >= NN) return;
  int e0 = rp[d0], e1 = rp[d0 + CH];
  int base_d = d0 - (d0 & (TN - 1));
  float a0 = 0.f, a1 = 0.f, a2 = 0.f, a3 = 0.f;
  float rg0 = 0.f, rg1 = 0.f, rg2 = 0.f, rg3 = 0.f;
  int cur = -1, curg = -1;
  unsigned int wmask = 0u;

  auto gflush = [&]() {
    if (curg >= 0) {
      float* pp = pool + curg * 256 + lane * 4;
      atomicAdd(pp + 0, rg0); atomicAdd(pp + 1, rg1);
      atomicAdd(pp + 2, rg2); atomicAdd(pp + 3, rg3);
      rg0 = rg1 = rg2 = rg3 = 0.f;
    }
  };
  auto dflush = [&](int rel) {
    int d = base_d + rel;
    wmask |= 1u << (d - d0);
    float di = dinv[d];
    uint2 zv = *(const uint2*)(zz + ((size_t)d << 8) + lane * 4);
    int g = batch[d];
    if (g != curg) { gflush(); curg = g; }
    rg0 += di * (a0 + bflo(zv.x)); rg1 += di * (a1 + bfhi(zv.x));
    rg2 += di * (a2 + bflo(zv.y)); rg3 += di * (a3 + bfhi(zv.y));
    a0 = a1 = a2 = a3 = 0.f;
  };

  unsigned int pk = 0u;
  if (e0 + lane < e1) pk = csr_pk[e0 + lane];
  for (int bb = e0; bb < e1; bb += 64) {
    int n = min(64, e1 - bb);
    unsigned int npk = 0u;
    if (bb + 64 + lane < e1) npk = csr_pk[bb + 64 + lane];
    for (int q = 0; q < n; q += 8) {
      int m = n - q; m = m > 8 ? 8 : m;
      unsigned int p[8]; uint2 vv[8];
      if (m == 8) {
#pragma unroll
        for (int t = 0; t < 8; ++t) p[t] = (unsigned int)__shfl((int)pk, q + t, 64);
#pragma unroll
        for (int t = 0; t < 8; ++t)
          vv[t] = *(const uint2*)(zz + ((size_t)(p[t] & 0xffffu) << 8) + lane * 4);
#pragma unroll
        for (int t = 0; t < 8; ++t) {
          int rel = (int)(p[t] >> 16);
          if (rel != cur) { if (cur >= 0) dflush(cur); cur = rel; }
          a0 += bflo(vv[t].x); a1 += bfhi(vv[t].x);
          a2 += bflo(vv[t].y); a3 += bfhi(vv[t].y);
        }
      } else {
#pragma unroll
        for (int t = 0; t < 8; ++t) if (t < m)
          p[t] = (unsigned int)__shfl((int)pk, q + t, 64);
#pragma unroll
        for (int t = 0; t < 8; ++t) if (t < m)
          vv[t] = *(const uint2*)(zz + ((size_t)(p[t] & 0xffffu) << 8) + lane * 4);
#pragma unroll
        for (int t = 0; t < 8; ++t) if (t < m) {
          int rel = (int)(p[t] >> 16);
          if (rel != cur) { if (cur >= 0) dflush(cur); cur = rel; }
          a0 += bflo(vv[t].x); a1 += bfhi(vv[t].x);
          a2 += bflo(vv[t].y); a3 += bfhi(vv[t].y);
        }
      }
    }
    pk = npk;
  }
  if (cur >= 0) dflush(cur);
#pragma unroll
  for (int j = 0; j < CH; ++j)
    if (!((wmask >> j) & 1u)) dflush((d0 & (TN - 1)) + j);
  gflush();
}

// ---------------- f = (pool/c) @ W2 + b2 ----------------
__global__ __launch_bounds__(256) void k_featF(const float* __restrict__ pool_s,
                                               const float* __restrict__ pool_n,
                                               const int* __restrict__ st_s,
                                               const int* __restrict__ st_n,
                                               const float* __restrict__ W2,
                                               const float* __restrict__ b2,
                                               float* __restrict__ fstate,
                                               float* __restrict__ fnext,
                                               float* __restrict__ out) {
  int g = blockIdx.x, which = blockIdx.y, j = threadIdx.x;
  const float* pool = which ? pool_n : pool_s;
  const int* st = which ? st_n : st_s;
  int c = st[g + 1] - st[g];
  __shared__ float v[256];
  float cc = fmaxf((float)c, 1.0f);
  v[j] = pool[g * 256 + j] / cc;
  __syncthreads();
  float acc = 0.f;
  for (int k = 0; k < 256; ++k) acc += v[k] * W2[k * 256 + j];
  float val = (c > 0) ? (acc + b2[j]) : 0.f;
  if (which) { fnext[g * 256 + j] = val; out[g * 256 + j] = val; }
  else fstate[g * 256 + j] = val;
}

// ---------------- heads ----------------
__global__ __launch_bounds__(256) void k_head(const float* __restrict__ fstate,
                                              const float* __restrict__ fnext,
                                              const int* __restrict__ action,
                                              const float* __restrict__ Wf, const float* __restrict__ bfv,
                                              const float* __restrict__ Wi1, const float* __restrict__ bi1,
                                              const float* __restrict__ Wi2, const float* __restrict__ bi2,
                                              const float* __restrict__ Wi3, const float* __restrict__ bi3,
                                              float* __restrict__ out) {
  int g = blockIdx.x, j = threadIdx.x;
  __shared__ float fs[256], fn_[256], z1[128], z2[128];
  fs[j] = fstate[g * 256 + j];
  fn_[j] = fnext[g * 256 + j];
  __syncthreads();
  int a = action[g];
  float acc = bfv[j] + Wf[a * 256 + j];
  for (int k = 0; k < 256; ++k) acc += fs[k] * Wf[(16 + k) * 256 + j];
  out[16384 + g * 256 + j] = acc;
  if (j < 128) {
    float t = bi1[j];
    for (int k = 0; k < 256; ++k)
      t += fs[k] * Wi1[k * 128 + j] + fn_[k] * Wi1[(256 + k) * 128 + j];
    z1[j] = fmaxf(t, 0.f);
  }
  __syncthreads();
  if (j < 128) {
    float t = bi2[j];
    for (int k = 0; k < 128; ++k) t += z1[k] * Wi2[k * 128 + j];
    z2[j] = fmaxf(t, 0.f);
  }
  __syncthreads();
  if (j < 16) {
    float t = bi3[j];
    for (int k = 0; k < 128; ++k) t += z2[k] * Wi3[k * 16 + j];
    out[32768 + g * 16 + j] = t;
  }
}

// ---------------- workspace layout ----------------
static constexpr size_t AL(size_t x) { return (x + 255) & ~(size_t)255; }
static constexpr size_t O_XB   = 0;                                    // 25.6 MB
static constexpr size_t O_H1   = O_XB + AL((size_t)MPAD * DD * 2);     // 25.6 MB (sort scratch aliases)
static constexpr size_t O_Z    = O_H1 + AL((size_t)MPAD * DD * 2);     // 25.6 MB row-major z'
static constexpr size_t O_CSRS = O_Z + AL((size_t)NN * DD * 2);
static constexpr size_t O_RP   = O_CSRS + AL((size_t)NE * 4);
static constexpr size_t O_DINV = O_RP + AL((size_t)(NN + 1) * 4);
static constexpr size_t O_DEG  = O_DINV + AL((size_t)NN * 4);
static constexpr size_t O_BS   = O_DEG + AL((size_t)NN * 4);
static constexpr size_t O_ST0  = O_BS + AL(256 * 4);
static constexpr size_t O_ST1  = O_ST0 + AL((NG + 1) * 4);
static constexpr size_t O_WT   = O_ST1 + AL((NG + 1) * 4);
static constexpr size_t O_PS   = O_WT + AL((size_t)DD * DD * 2);
static constexpr size_t O_PN   = O_PS + AL((size_t)NG * DD * 4);
static constexpr size_t O_FS   = O_PN + AL((size_t)NG * DD * 4);
static constexpr size_t O_FN   = O_FS + AL((size_t)NG * DD * 4);
static constexpr size_t O_END  = O_FN + AL((size_t)NG * DD * 4);
// aliased scratch (inside h1, used only before k_gemm writes h1):
static constexpr size_t O_PART = O_H1;                                  // HC*NN/2 u32 = 6.4 MB
static constexpr size_t O_BASE = O_H1 + AL((size_t)HC * (NN / 2) * 4);  // HC*NN u32 = 12.8 MB

extern "C" void kernel_launch(void* const* d_in, const int* in_sizes, int n_in,
                              void* d_out, int out_size, void* d_ws, size_t ws_size,
                              hipStream_t stream) {
  const float* x_s     = (const float*)d_in[0];
  const int*   ei_s    = (const int*)d_in[1];
  const int*   batch_s = (const int*)d_in[2];
  const float* x_n     = (const float*)d_in[3];
  const int*   ei_n    = (const int*)d_in[4];
  const int*   batch_n = (const int*)d_in[5];
  const int*   action  = (const int*)d_in[6];
  const float* W1      = (const float*)d_in[7];
  const float* b1      = (const float*)d_in[8];
  const float* W2      = (const float*)d_in[9];
  const float* b2      = (const float*)d_in[10];
  const float* Wf      = (const float*)d_in[11];
  const float* bfv     = (const float*)d_in[12];
  const float* Wi1     = (const float*)d_in[13];
  const float* bi1     = (const float*)d_in[14];
  const float* Wi2     = (const float*)d_in[15];
  const float* bi2     = (const float*)d_in[16];
  const float* Wi3     = (const float*)d_in[17];
  const float* bi3     = (const float*)d_in[18];
  float* out = (float*)d_out;
  char* ws = (char*)d_ws;
  if (ws_size < O_END) return;

  unsigned short* xb  = (unsigned short*)(ws + O_XB);
  unsigned short* h1  = (unsigned short*)(ws + O_H1);
  unsigned short* zb  = (unsigned short*)(ws + O_Z);
  unsigned int* csr_pk = (unsigned int*)(ws + O_CSRS);
  int*   rp      = (int*)(ws + O_RP);
  float* dinv    = (float*)(ws + O_DINV);
  int*   deg     = (int*)(ws + O_DEG);
  int*   bsums   = (int*)(ws + O_BS);
  unsigned short* Wt = (unsigned short*)(ws + O_WT);
  float* fstate  = (float*)(ws + O_FS);
  float* fnext   = (float*)(ws + O_FN);
  int*   starts[2] = { (int*)(ws + O_ST0), (int*)(ws + O_ST1) };
  float* pool[2]   = { (float*)(ws + O_PS), (float*)(ws + O_PN) };
  unsigned int* partial = (unsigned int*)(ws + O_PART);
  int*          basebuf = (int*)(ws + O_BASE);

  // zero both pool accumulators (agg2w uses atomics)
  k_zero<<<64, 256, 0, stream>>>((unsigned int*)(ws + O_PS), 2 * NG * DD);
  k_castW<<<(DD * DD) / 256, 256, 0, stream>>>(W1, Wt);

  const float* xs[2]  = { x_s, x_n };
  const int*   eis[2] = { ei_s, ei_n };
  const int*   bts[2] = { batch_s, batch_n };

  for (int gidx = 0; gidx < 2; ++gidx) {
    const float* x = xs[gidx];
    const int* src = eis[gidx];
    const int* dst = eis[gidx] + NE;
    const int* batch = bts[gidx];

    k_castX<<<(MPAD * DD / 4) / 256, 256, 0, stream>>>(x, xb);

    // --- in-CSR (by dst): deg/dinv, rp, csr_pk ---
    k_hist2<<<dim3(HC, 2), 256, 0, stream>>>(dst, partial);
    k_reduce<<<(NN / 2 + 255) / 256, 256, 0, stream>>>(partial, deg, dinv);
    k_bsum<<<SB, 256, 0, stream>>>(deg, bsums);
    k_sscan<<<1, 256, 0, stream>>>(bsums);
    k_fillrp<<<SB, 256, 0, stream>>>(deg, bsums, rp);
    k_base<<<(NN + 255) / 256, 256, 0, stream>>>((const unsigned short*)partial, rp, basebuf);
    k_fill2<<<dim3(HC, (NN + FBINS - 1) / FBINS), 256, 0, stream>>>(src, dst, basebuf, csr_pk);
    k_bounds<<<(NN + 1 + 255) / 256, 256, 0, stream>>>(batch, starts[gidx]);

    // --- dense GEMM with dinv pre-scale (frees sort scratch), then wave aggregations ---
    k_gemm<<<dim3(MPAD / 128, DD / 64), 256, 0, stream>>>(xb, Wt, dinv, h1);
    int nwaves = NN / CH;                      // 12500
    int nblk = (nwaves + 3) / 4;               // 3125
    k_agg1w<<<nblk, 256, 0, stream>>>(h1, csr_pk, rp, dinv, b1, zb);
    k_agg2w<<<nblk, 256, 0, stream>>>(zb, csr_pk, rp, dinv, batch, pool[gidx]);
  }

  k_featF<<<dim3(NG, 2), 256, 0, stream>>>(pool[0], pool[1], starts[0], starts[1], W2, b2,
                                           fstate, fnext, out);
  k_head<<<NG, 256, 0, stream>>>(fstate, fnext, action, Wf, bfv,
                                 Wi1, bi1, Wi2, bi2, Wi3, bi3, out);
}

// Round 13
// 580.740 us; speedup vs baseline: 1.0838x; 1.0838x over previous
//
#include <hip/hip_runtime.h>

#define NN 50000
#define NE 800000
#define DD 256
#define NG 64
#define MPAD 50048  // 128 * 391

// counting-sort parameters
#define HC 64          // edge chunks (NE/HC = 12500)
#define EPC (NE / HC)  // 12500
#define HBINS 32768    // bins/part, u16-packed -> 64 KB LDS (2 parts)
#define FBINS 16384    // bins/part, u32 counters -> 64 KB LDS (4 parts)

// parallel scan
#define SB 196         // SB*256 = 50176 >= NN+1

// aggregation
#define TN 128         // rel packing block (dst & 127)
#define CH 8           // dsts per wave (128 % CH == 0 -> chunk never straddles a 128-block)

typedef __attribute__((ext_vector_type(8))) short bf16x8;
typedef __attribute__((ext_vector_type(4))) float f32x4;

__device__ __forceinline__ float bf2f(unsigned short u) {
  union { unsigned int i; float f; } v; v.i = ((unsigned int)u) << 16; return v.f;
}
__device__ __forceinline__ unsigned short f2bf(float f) {
  union { float f; unsigned int i; } v; v.f = f;
  unsigned int x = v.i;
  x += 0x7fffu + ((x >> 16) & 1u);  // RNE
  return (unsigned short)(x >> 16);
}
__device__ __forceinline__ float bflo(unsigned int w) {
  union { unsigned int i; float f; } v; v.i = w << 16; return v.f;
}
__device__ __forceinline__ float bfhi(unsigned int w) {
  union { unsigned int i; float f; } v; v.i = w & 0xffff0000u; return v.f;
}

// ---------------- init / casts ----------------
__global__ void k_zero(unsigned int* __restrict__ p, int n) {
  int i = blockIdx.x * blockDim.x + threadIdx.x;
  int st = gridDim.x * blockDim.x;
  for (; i < n; i += st) p[i] = 0u;
}

__global__ void k_castW(const float* __restrict__ W, unsigned short* __restrict__ Wt) {
  int i = blockIdx.x * blockDim.x + threadIdx.x;
  int n = i >> 8, k = i & 255;
  Wt[i] = f2bf(W[k * 256 + n]);
}

__global__ void k_castX(const float* __restrict__ x, unsigned short* __restrict__ xb) {
  int i = blockIdx.x * blockDim.x + threadIdx.x;
  int e = i * 4;
  int row = e >> 8;
  float4 v = make_float4(0.f, 0.f, 0.f, 0.f);
  if (row < NN) v = *(const float4*)(x + e);
  ushort4 u;
  u.x = f2bf(v.x); u.y = f2bf(v.y); u.z = f2bf(v.z); u.w = f2bf(v.w);
  *(ushort4*)(xb + e) = u;
}

// ---------------- GEMM: h1'[row][col] = dinv[row] * (A @ B), row-major ----------------
__global__ __launch_bounds__(256) void k_gemm(const unsigned short* __restrict__ A,
                                              const unsigned short* __restrict__ Bt,
                                              const float* __restrict__ dinv,
                                              unsigned short* __restrict__ C) {
  __shared__ unsigned short As[128][40];
  __shared__ unsigned short Bs[64][40];
  int tid = threadIdx.x;
  int lane = tid & 63;
  int wave = tid >> 6;
  int wm = wave >> 1, wn = wave & 1;
  int m0 = blockIdx.x * 128, n0 = blockIdx.y * 64;
  int l15 = lane & 15, l4 = lane >> 4;
  f32x4 acc[4][2] = {};

  for (int ks = 0; ks < 8; ++ks) {
    int k0 = ks * 32;
    {
      int c = tid, r = c >> 2, cc = c & 3;
      *(uint4*)(&As[r][cc * 8]) = *(const uint4*)(A + (size_t)(m0 + r) * 256 + k0 + cc * 8);
      c = tid + 256; r = c >> 2; cc = c & 3;
      *(uint4*)(&As[r][cc * 8]) = *(const uint4*)(A + (size_t)(m0 + r) * 256 + k0 + cc * 8);
      c = tid; r = c >> 2; cc = c & 3;
      *(uint4*)(&Bs[r][cc * 8]) = *(const uint4*)(Bt + (size_t)(n0 + r) * 256 + k0 + cc * 8);
    }
    __syncthreads();
    bf16x8 a[4], b[2];
#pragma unroll
    for (int fm = 0; fm < 4; ++fm)
      a[fm] = *(const bf16x8*)(&As[wm * 64 + fm * 16 + l15][l4 * 8]);
#pragma unroll
    for (int fn = 0; fn < 2; ++fn)
      b[fn] = *(const bf16x8*)(&Bs[wn * 32 + fn * 16 + l15][l4 * 8]);
#pragma unroll
    for (int fm = 0; fm < 4; ++fm)
#pragma unroll
      for (int fn = 0; fn < 2; ++fn)
        acc[fm][fn] = __builtin_amdgcn_mfma_f32_16x16x32_bf16(a[fm], b[fn], acc[fm][fn], 0, 0, 0);
    __syncthreads();
  }
  int r0 = l4 * 4;
#pragma unroll
  for (int fm = 0; fm < 4; ++fm)
#pragma unroll
    for (int fn = 0; fn < 2; ++fn) {
      int row = m0 + wm * 64 + fm * 16 + r0;
      int col = n0 + wn * 32 + fn * 16 + l15;
#pragma unroll
      for (int r = 0; r < 4; ++r) {
        int rr = row + r;
        float dv = dinv[rr < NN ? rr : 0];
        C[(size_t)rr * 256 + col] = f2bf(dv * acc[fm][fn][r]);
      }
    }
}

// ---------------- counting sort (by dst) ----------------
__global__ __launch_bounds__(256) void k_hist2(const int* __restrict__ key,
                                               unsigned int* __restrict__ partial) {
  __shared__ unsigned int lh[HBINS / 2];  // 64 KB u16-packed
  int tid = threadIdx.x;
  int c = blockIdx.x, p = blockIdx.y;
  for (int w = tid; w < HBINS / 2; w += 256) lh[w] = 0u;
  __syncthreads();
  int lo = c * EPC, hi = lo + EPC;
  int b0 = p * HBINS;
  for (int i = lo + tid; i < hi; i += 256) {
    int rel = key[i] - b0;
    if ((unsigned)rel < (unsigned)HBINS)
      atomicAdd(&lh[rel >> 1], 1u << ((rel & 1) * 16));
  }
  __syncthreads();
  int wbase = p * (HBINS / 2);
  for (int w = tid; w < HBINS / 2; w += 256) {
    int gw = wbase + w;
    if (gw < NN / 2) partial[(size_t)c * (NN / 2) + gw] = lh[w];
  }
}

// reduce partials -> deg AND dinv
__global__ void k_reduce(const unsigned int* __restrict__ partial, int* __restrict__ deg,
                         float* __restrict__ dinv) {
  int w = blockIdx.x * blockDim.x + threadIdx.x;
  if (w >= NN / 2) return;
  unsigned int sl = 0, sh = 0;
#pragma unroll
  for (int c = 0; c < HC; ++c) {
    unsigned int v = partial[(size_t)c * (NN / 2) + w];
    sl += v & 0xffffu;
    sh += v >> 16;
  }
  *(int2*)(deg + 2 * w) = make_int2((int)sl, (int)sh);
  dinv[2 * w] = rsqrtf((float)sl + 1.0f);
  dinv[2 * w + 1] = rsqrtf((float)sh + 1.0f);
}

// 3-dispatch parallel exclusive scan: deg[NN] -> rp[NN+1]
__global__ __launch_bounds__(256) void k_bsum(const int* __restrict__ deg, int* __restrict__ bsums) {
  __shared__ int s[256];
  int b = blockIdx.x, t = threadIdx.x, i = b * 256 + t;
  int v = (i < NN) ? deg[i] : 0;
  s[t] = v; __syncthreads();
  for (int off = 128; off > 0; off >>= 1) {
    if (t < off) s[t] += s[t + off];
    __syncthreads();
  }
  if (t == 0) bsums[b] = s[0];
}
__global__ __launch_bounds__(256) void k_sscan(int* __restrict__ bsums) {
  __shared__ int s[256];
  int t = threadIdx.x;
  int v = (t < SB) ? bsums[t] : 0;
  s[t] = v; __syncthreads();
  for (int off = 1; off < 256; off <<= 1) {
    int tmp = (t >= off) ? s[t - off] : 0;
    __syncthreads();
    s[t] += tmp;
    __syncthreads();
  }
  if (t < SB) bsums[t] = s[t] - v;  // exclusive
}
__global__ __launch_bounds__(256) void k_fillrp(const int* __restrict__ deg,
                                                const int* __restrict__ bsums,
                                                int* __restrict__ rp) {
  __shared__ int s[256];
  int b = blockIdx.x, t = threadIdx.x, i = b * 256 + t;
  int v = (i < NN) ? deg[i] : 0;
  s[t] = v; __syncthreads();
  for (int off = 1; off < 256; off <<= 1) {
    int tmp = (t >= off) ? s[t - off] : 0;
    __syncthreads();
    s[t] += tmp;
    __syncthreads();
  }
  int excl = bsums[b] + s[t] - v;
  if (i <= NN) rp[i] = excl;
}

// base[c][b] = rp[b] + sum_{c'<c} partial16[c'][b]
__global__ void k_base(const unsigned short* __restrict__ partial16,
                       const int* __restrict__ rp, int* __restrict__ base) {
  int b = blockIdx.x * blockDim.x + threadIdx.x;
  if (b >= NN) return;
  int run = rp[b];
#pragma unroll
  for (int c = 0; c < HC; ++c) {
    base[(size_t)c * NN + b] = run;
    run += (int)partial16[(size_t)c * NN + b];
  }
}

// graph boundaries from sorted batch
__global__ void k_bounds(const int* __restrict__ batch, int* __restrict__ starts) {
  int i = blockIdx.x * blockDim.x + threadIdx.x;
  if (i > NN) return;
  if (i == 0) {
    int b0 = batch[0];
    for (int g = 0; g <= b0; ++g) starts[g] = 0;
  } else if (i == NN) {
    int bl = batch[NN - 1];
    for (int g = bl + 1; g <= NG; ++g) starts[g] = NN;
  } else {
    int a = batch[i - 1], b = batch[i];
    for (int g = a + 1; g <= b; ++g) starts[g] = i;
  }
}

// in-CSR fill (keyed by dst): csr_pk = ((dst&127)<<25) | (src<<9)
// (src<<9 is the byte offset of row src at 512 B/row; max 49999*512 < 2^25)
__global__ __launch_bounds__(256) void k_fill2(const int* __restrict__ src,
                                               const int* __restrict__ dst,
                                               const int* __restrict__ base,
                                               unsigned int* __restrict__ csr_pk) {
  __shared__ unsigned int pos[FBINS];  // 64 KB
  int tid = threadIdx.x;
  int c = blockIdx.x, p = blockIdx.y;
  int b0 = p * FBINS;
  for (int w = tid; w < FBINS; w += 256) {
    int gb = b0 + w;
    pos[w] = (gb < NN) ? (unsigned int)base[(size_t)c * NN + gb] : 0u;
  }
  __syncthreads();
  int lo = c * EPC, hi = lo + EPC;
  for (int i = lo + tid; i < hi; i += 256) {
    int d = dst[i];
    int s = src[i];
    int rel = d - b0;
    if ((unsigned)rel < (unsigned)FBINS) {
      int idx = (int)atomicAdd(&pos[rel], 1u);
      csr_pk[idx] = ((unsigned int)(d & (TN - 1)) << 25) | ((unsigned int)s << 9);
    }
  }
}

// ---------------- conv1: wave-per-CH-dsts, full 256-feature row per edge ----------------
// z' = dinv * elu(dinv*(sum h1'[src] + h1'[d]) + b1). No LDS, no atomics, no barriers.
// 16-deep gather batches; run-detection flush is wave-uniform; deg-0 dsts via mask sweep.
__global__ __launch_bounds__(256) void k_agg1w(const unsigned short* __restrict__ h1,
                                               const unsigned int* __restrict__ csr_pk,
                                               const int* __restrict__ rp,
                                               const float* __restrict__ dinv,
                                               const float* __restrict__ b1,
                                               unsigned short* __restrict__ z) {
  int wid = blockIdx.x * 4 + (threadIdx.x >> 6);
  int lane = threadIdx.x & 63;
  int d0 = wid * CH;
  if (d0 >= NN) return;
  float4 b1v = *(const float4*)(b1 + lane * 4);
  int e0 = rp[d0], e1 = rp[d0 + CH];
  int base_d = d0 - (d0 & (TN - 1));
  const char* h1b = (const char*)h1;
  int lane8 = lane * 8;
  float a0 = 0.f, a1 = 0.f, a2 = 0.f, a3 = 0.f;
  int cur = -1;
  unsigned int wmask = 0u;

  auto flushz = [&](int rel) {
    int d = base_d + rel;
    wmask |= 1u << (d - d0);
    float di = dinv[d];
    uint2 hv = *(const uint2*)(h1b + ((size_t)d << 9) + lane8);
    float u0 = di * (a0 + bflo(hv.x)) + b1v.x;
    float u1 = di * (a1 + bfhi(hv.x)) + b1v.y;
    float u2 = di * (a2 + bflo(hv.y)) + b1v.z;
    float u3 = di * (a3 + bfhi(hv.y)) + b1v.w;
    u0 = u0 > 0.f ? u0 : expm1f(u0);
    u1 = u1 > 0.f ? u1 : expm1f(u1);
    u2 = u2 > 0.f ? u2 : expm1f(u2);
    u3 = u3 > 0.f ? u3 : expm1f(u3);
    uint2 ow;
    ow.x = (unsigned int)f2bf(di * u0) | ((unsigned int)f2bf(di * u1) << 16);
    ow.y = (unsigned int)f2bf(di * u2) | ((unsigned int)f2bf(di * u3) << 16);
    *(uint2*)((char*)z + ((size_t)d << 9) + lane8) = ow;
    a0 = a1 = a2 = a3 = 0.f;
  };

  unsigned int pk = 0u;
  if (e0 + lane < e1) pk = csr_pk[e0 + lane];
  for (int bb = e0; bb < e1; bb += 64) {
    int n = min(64, e1 - bb);
    unsigned int npk = 0u;
    if (bb + 64 + lane < e1) npk = csr_pk[bb + 64 + lane];
    for (int q = 0; q < n; q += 16) {
      int m = n - q; m = m > 16 ? 16 : m;
      unsigned int p[16]; uint2 vv[16];
      if (m == 16) {
#pragma unroll
        for (int t = 0; t < 16; ++t) p[t] = (unsigned int)__shfl((int)pk, q + t, 64);
#pragma unroll
        for (int t = 0; t < 16; ++t)
          vv[t] = *(const uint2*)(h1b + (p[t] & 0x1FFFFFFu) + lane8);
#pragma unroll
        for (int t = 0; t < 16; ++t) {
          int rel = (int)(p[t] >> 25);
          if (rel != cur) { if (cur >= 0) flushz(cur); cur = rel; }
          a0 += bflo(vv[t].x); a1 += bfhi(vv[t].x);
          a2 += bflo(vv[t].y); a3 += bfhi(vv[t].y);
        }
      } else {
#pragma unroll
        for (int t = 0; t < 16; ++t) if (t < m)
          p[t] = (unsigned int)__shfl((int)pk, q + t, 64);
#pragma unroll
        for (int t = 0; t < 16; ++t) if (t < m)
          vv[t] = *(const uint2*)(h1b + (p[t] & 0x1FFFFFFu) + lane8);
#pragma unroll
        for (int t = 0; t < 16; ++t) if (t < m) {
          int rel = (int)(p[t] >> 25);
          if (rel != cur) { if (cur >= 0) flushz(cur); cur = rel; }
          a0 += bflo(vv[t].x); a1 += bfhi(vv[t].x);
          a2 += bflo(vv[t].y); a3 += bfhi(vv[t].y);
        }
      }
    }
    pk = npk;
  }
  if (cur >= 0) flushz(cur);
#pragma unroll
  for (int j = 0; j < CH; ++j)
    if (!((wmask >> j) & 1u)) flushz((d0 & (TN - 1)) + j);
}

// ---------------- conv2+pool: same skeleton over z'; per-graph reg acc -> atomic pool ----
__global__ __launch_bounds__(256) void k_agg2w(const unsigned short* __restrict__ zz,
                                               const unsigned int* __restrict__ csr_pk,
                                               const int* __restrict__ rp,
                                               const float* __restrict__ dinv,
                                               const int* __restrict__ batch,
                                               float* __restrict__ pool) {
  int wid = blockIdx.x * 4 + (threadIdx.x >> 6);
  int lane = threadIdx.x & 63;
  int d0 = wid * CH;
  if (d0 >= NN) return;
  int e0 = rp[d0], e1 = rp[d0 + CH];
  int base_d = d0 - (d0 & (TN - 1));
  const char* zb8 = (const char*)zz;
  int lane8 = lane * 8;
  float a0 = 0.f, a1 = 0.f, a2 = 0.f, a3 = 0.f;
  float rg0 = 0.f, rg1 = 0.f, rg2 = 0.f, rg3 = 0.f;
  int cur = -1, curg = -1;
  unsigned int wmask = 0u;

  auto gflush = [&]() {
    if (curg >= 0) {
      float* pp = pool + curg * 256 + lane * 4;
      atomicAdd(pp + 0, rg0); atomicAdd(pp + 1, rg1);
      atomicAdd(pp + 2, rg2); atomicAdd(pp + 3, rg3);
      rg0 = rg1 = rg2 = rg3 = 0.f;
    }
  };
  auto dflush = [&](int rel) {
    int d = base_d + rel;
    wmask |= 1u << (d - d0);
    float di = dinv[d];
    uint2 zv = *(const uint2*)(zb8 + ((size_t)d << 9) + lane8);
    int g = batch[d];
    if (g != curg) { gflush(); curg = g; }
    rg0 += di * (a0 + bflo(zv.x)); rg1 += di * (a1 + bfhi(zv.x));
    rg2 += di * (a2 + bflo(zv.y)); rg3 += di * (a3 + bfhi(zv.y));
    a0 = a1 = a2 = a3 = 0.f;
  };

  unsigned int pk = 0u;
  if (e0 + lane < e1) pk = csr_pk[e0 + lane];
  for (int bb = e0; bb < e1; bb += 64) {
    int n = min(64, e1 - bb);
    unsigned int npk = 0u;
    if (bb + 64 + lane < e1) npk = csr_pk[bb + 64 + lane];
    for (int q = 0; q < n; q += 16) {
      int m = n - q; m = m > 16 ? 16 : m;
      unsigned int p[16]; uint2 vv[16];
      if (m == 16) {
#pragma unroll
        for (int t = 0; t < 16; ++t) p[t] = (unsigned int)__shfl((int)pk, q + t, 64);
#pragma unroll
        for (int t = 0; t < 16; ++t)
          vv[t] = *(const uint2*)(zb8 + (p[t] & 0x1FFFFFFu) + lane8);
#pragma unroll
        for (int t = 0; t < 16; ++t) {
          int rel = (int)(p[t] >> 25);
          if (rel != cur) { if (cur >= 0) dflush(cur); cur = rel; }
          a0 += bflo(vv[t].x); a1 += bfhi(vv[t].x);
          a2 += bflo(vv[t].y); a3 += bfhi(vv[t].y);
        }
      } else {
#pragma unroll
        for (int t = 0; t < 16; ++t) if (t < m)
          p[t] = (unsigned int)__shfl((int)pk, q + t, 64);
#pragma unroll
        for (int t = 0; t < 16; ++t) if (t < m)
          vv[t] = *(const uint2*)(zb8 + (p[t] & 0x1FFFFFFu) + lane8);
#pragma unroll
        for (int t = 0; t < 16; ++t) if (t < m) {
          int rel = (int)(p[t] >> 25);
          if (rel != cur) { if (cur >= 0) dflush(cur); cur = rel; }
          a0 += bflo(vv[t].x); a1 += bfhi(vv[t].x);
          a2 += bflo(vv[t].y); a3 += bfhi(vv[t].y);
        }
      }
    }
    pk = npk;
  }
  if (cur >= 0) dflush(cur);
#pragma unroll
  for (int j = 0; j < CH; ++j)
    if (!((wmask >> j) & 1u)) dflush((d0 & (TN - 1)) + j);
  gflush();
}

// ---------------- f = (pool/c) @ W2 + b2 ----------------
__global__ __launch_bounds__(256) void k_featF(const float* __restrict__ pool_s,
                                               const float* __restrict__ pool_n,
                                               const int* __restrict__ st_s,
                                               const int* __restrict__ st_n,
                                               const float* __restrict__ W2,
                                               const float* __restrict__ b2,
                                               float* __restrict__ fstate,
                                               float* __restrict__ fnext,
                                               float* __restrict__ out) {
  int g = blockIdx.x, which = blockIdx.y, j = threadIdx.x;
  const float* pool = which ? pool_n : pool_s;
  const int* st = which ? st_n : st_s;
  int c = st[g + 1] - st[g];
  __shared__ float v[256];
  float cc = fmaxf((float)c, 1.0f);
  v[j] = pool[g * 256 + j] / cc;
  __syncthreads();
  float acc = 0.f;
  for (int k = 0; k < 256; ++k) acc += v[k] * W2[k * 256 + j];
  float val = (c > 0) ? (acc + b2[j]) : 0.f;
  if (which) { fnext[g * 256 + j] = val; out[g * 256 + j] = val; }
  else fstate[g * 256 + j] = val;
}

// ---------------- heads ----------------
__global__ __launch_bounds__(256) void k_head(const float* __restrict__ fstate,
                                              const float* __restrict__ fnext,
                                              const int* __restrict__ action,
                                              const float* __restrict__ Wf, const float* __restrict__ bfv,
                                              const float* __restrict__ Wi1, const float* __restrict__ bi1,
                                              const float* __restrict__ Wi2, const float* __restrict__ bi2,
                                              const float* __restrict__ Wi3, const float* __restrict__ bi3,
                                              float* __restrict__ out) {
  int g = blockIdx.x, j = threadIdx.x;
  __shared__ float fs[256], fn_[256], z1[128], z2[128];
  fs[j] = fstate[g * 256 + j];
  fn_[j] = fnext[g * 256 + j];
  __syncthreads();
  int a = action[g];
  float acc = bfv[j] + Wf[a * 256 + j];
  for (int k = 0; k < 256; ++k) acc += fs[k] * Wf[(16 + k) * 256 + j];
  out[16384 + g * 256 + j] = acc;
  if (j < 128) {
    float t = bi1[j];
    for (int k = 0; k < 256; ++k)
      t += fs[k] * Wi1[k * 128 + j] + fn_[k] * Wi1[(256 + k) * 128 + j];
    z1[j] = fmaxf(t, 0.f);
  }
  __syncthreads();
  if (j < 128) {
    float t = bi2[j];
    for (int k = 0; k < 128; ++k) t += z1[k] * Wi2[k * 128 + j];
    z2[j] = fmaxf(t, 0.f);
  }
  __syncthreads();
  if (j < 16) {
    float t = bi3[j];
    for (int k = 0; k < 128; ++k) t += z2[k] * Wi3[k * 16 + j];
    out[32768 + g * 16 + j] = t;
  }
}

// ---------------- workspace layout ----------------
static constexpr size_t AL(size_t x) { return (x + 255) & ~(size_t)255; }
static constexpr size_t O_XB   = 0;                                    // 25.6 MB
static constexpr size_t O_H1   = O_XB + AL((size_t)MPAD * DD * 2);     // 25.6 MB (sort scratch aliases)
static constexpr size_t O_Z    = O_H1 + AL((size_t)MPAD * DD * 2);     // 25.6 MB row-major z'
static constexpr size_t O_CSRS = O_Z + AL((size_t)NN * DD * 2);
static constexpr size_t O_RP   = O_CSRS + AL((size_t)NE * 4);
static constexpr size_t O_DINV = O_RP + AL((size_t)(NN + 1) * 4);
static constexpr size_t O_DEG  = O_DINV + AL((size_t)NN * 4);
static constexpr size_t O_BS   = O_DEG + AL((size_t)NN * 4);
static constexpr size_t O_ST0  = O_BS + AL(256 * 4);
static constexpr size_t O_ST1  = O_ST0 + AL((NG + 1) * 4);
static constexpr size_t O_WT   = O_ST1 + AL((NG + 1) * 4);
static constexpr size_t O_PS   = O_WT + AL((size_t)DD * DD * 2);
static constexpr size_t O_PN   = O_PS + AL((size_t)NG * DD * 4);
static constexpr size_t O_FS   = O_PN + AL((size_t)NG * DD * 4);
static constexpr size_t O_FN   = O_FS + AL((size_t)NG * DD * 4);
static constexpr size_t O_END  = O_FN + AL((size_t)NG * DD * 4);
// aliased scratch (inside h1, used only before k_gemm writes h1):
static constexpr size_t O_PART = O_H1;                                  // HC*NN/2 u32 = 6.4 MB
static constexpr size_t O_BASE = O_H1 + AL((size_t)HC * (NN / 2) * 4);  // HC*NN u32 = 12.8 MB

extern "C" void kernel_launch(void* const* d_in, const int* in_sizes, int n_in,
                              void* d_out, int out_size, void* d_ws, size_t ws_size,
                              hipStream_t stream) {
  const float* x_s     = (const float*)d_in[0];
  const int*   ei_s    = (const int*)d_in[1];
  const int*   batch_s = (const int*)d_in[2];
  const float* x_n     = (const float*)d_in[3];
  const int*   ei_n    = (const int*)d_in[4];
  const int*   batch_n = (const int*)d_in[5];
  const int*   action  = (const int*)d_in[6];
  const float* W1      = (const float*)d_in[7];
  const float* b1      = (const float*)d_in[8];
  const float* W2      = (const float*)d_in[9];
  const float* b2      = (const float*)d_in[10];
  const float* Wf      = (const float*)d_in[11];
  const float* bfv     = (const float*)d_in[12];
  const float* Wi1     = (const float*)d_in[13];
  const float* bi1     = (const float*)d_in[14];
  const float* Wi2     = (const float*)d_in[15];
  const float* bi2     = (const float*)d_in[16];
  const float* Wi3     = (const float*)d_in[17];
  const float* bi3     = (const float*)d_in[18];
  float* out = (float*)d_out;
  char* ws = (char*)d_ws;
  if (ws_size < O_END) return;

  unsigned short* xb  = (unsigned short*)(ws + O_XB);
  unsigned short* h1  = (unsigned short*)(ws + O_H1);
  unsigned short* zb  = (unsigned short*)(ws + O_Z);
  unsigned int* csr_pk = (unsigned int*)(ws + O_CSRS);
  int*   rp      = (int*)(ws + O_RP);
  float* dinv    = (float*)(ws + O_DINV);
  int*   deg     = (int*)(ws + O_DEG);
  int*   bsums   = (int*)(ws + O_BS);
  unsigned short* Wt = (unsigned short*)(ws + O_WT);
  float* fstate  = (float*)(ws + O_FS);
  float* fnext   = (float*)(ws + O_FN);
  int*   starts[2] = { (int*)(ws + O_ST0), (int*)(ws + O_ST1) };
  float* pool[2]   = { (float*)(ws + O_PS), (float*)(ws + O_PN) };
  unsigned int* partial = (unsigned int*)(ws + O_PART);
  int*          basebuf = (int*)(ws + O_BASE);

  // zero both pool accumulators (agg2w uses atomics)
  k_zero<<<64, 256, 0, stream>>>((unsigned int*)(ws + O_PS), 2 * NG * DD);
  k_castW<<<(DD * DD) / 256, 256, 0, stream>>>(W1, Wt);

  const float* xs[2]  = { x_s, x_n };
  const int*   eis[2] = { ei_s, ei_n };
  const int*   bts[2] = { batch_s, batch_n };

  for (int gidx = 0; gidx < 2; ++gidx) {
    const float* x = xs[gidx];
    const int* src = eis[gidx];
    const int* dst = eis[gidx] + NE;
    const int* batch = bts[gidx];

    k_castX<<<(MPAD * DD / 4) / 256, 256, 0, stream>>>(x, xb);

    // --- in-CSR (by dst): deg/dinv, rp, csr_pk ---
    k_hist2<<<dim3(HC, 2), 256, 0, stream>>>(dst, partial);
    k_reduce<<<(NN / 2 + 255) / 256, 256, 0, stream>>>(partial, deg, dinv);
    k_bsum<<<SB, 256, 0, stream>>>(deg, bsums);
    k_sscan<<<1, 256, 0, stream>>>(bsums);
    k_fillrp<<<SB, 256, 0, stream>>>(deg, bsums, rp);
    k_base<<<(NN + 255) / 256, 256, 0, stream>>>((const unsigned short*)partial, rp, basebuf);
    k_fill2<<<dim3(HC, (NN + FBINS - 1) / FBINS), 256, 0, stream>>>(src, dst, basebuf, csr_pk);
    k_bounds<<<(NN + 1 + 255) / 256, 256, 0, stream>>>(batch, starts[gidx]);

    // --- dense GEMM with dinv pre-scale (frees sort scratch), then wave aggregations ---
    k_gemm<<<dim3(MPAD / 128, DD / 64), 256, 0, stream>>>(xb, Wt, dinv, h1);
    int nwaves = NN / CH;                      // 6250
    int nblk = (nwaves + 3) / 4;               // 1563
    k_agg1w<<<nblk, 256, 0, stream>>>(h1, csr_pk, rp, dinv, b1, zb);
    k_agg2w<<<nblk, 256, 0, stream>>>(zb, csr_pk, rp, dinv, batch, pool[gidx]);
  }

  k_featF<<<dim3(NG, 2), 256, 0, stream>>>(pool[0], pool[1], starts[0], starts[1], W2, b2,
                                           fstate, fnext, out);
  k_head<<<NG, 256, 0, stream>>>(fstate, fnext, action, Wf, bfv,
                                 Wi1, bi1, Wi2, bi2, Wi3, bi3, out);
}

// Round 14
// 565.123 us; speedup vs baseline: 1.1137x; 1.0276x over previous
//
#include <hip/hip_runtime.h>

#define NN 50000
#define NE 800000
#define DD 256
#define NG 64
#define MPAD 50048  // 128 * 391

// counting-sort parameters
#define HC 64          // edge chunks (NE/HC = 12500)
#define EPC (NE / HC)  // 12500
#define HBINS 32768    // bins/part, u16-packed -> 64 KB LDS (2 parts)
#define FBINS 16384    // bins/part, u32 counters -> 64 KB LDS (4 parts)

// parallel scan
#define SB 196         // SB*256 = 50176 >= NN+1

// aggregation
#define TN 128         // rel packing block (dst & 127)
#define CH 8           // dsts per wave (128 % CH == 0 -> chunk never straddles a 128-block)

typedef __attribute__((ext_vector_type(8))) short bf16x8;
typedef __attribute__((ext_vector_type(4))) float f32x4;

__device__ __forceinline__ float bf2f(unsigned short u) {
  union { unsigned int i; float f; } v; v.i = ((unsigned int)u) << 16; return v.f;
}
__device__ __forceinline__ unsigned short f2bf(float f) {
  union { float f; unsigned int i; } v; v.f = f;
  unsigned int x = v.i;
  x += 0x7fffu + ((x >> 16) & 1u);  // RNE
  return (unsigned short)(x >> 16);
}
__device__ __forceinline__ float bflo(unsigned int w) {
  union { unsigned int i; float f; } v; v.i = w << 16; return v.f;
}
__device__ __forceinline__ float bfhi(unsigned int w) {
  union { unsigned int i; float f; } v; v.i = w & 0xffff0000u; return v.f;
}

// ---------------- init / casts ----------------
__global__ void k_zero(unsigned int* __restrict__ p, int n) {
  int i = blockIdx.x * blockDim.x + threadIdx.x;
  int st = gridDim.x * blockDim.x;
  for (; i < n; i += st) p[i] = 0u;
}

__global__ void k_castW(const float* __restrict__ W, unsigned short* __restrict__ Wt) {
  int i = blockIdx.x * blockDim.x + threadIdx.x;
  int n = i >> 8, k = i & 255;
  Wt[i] = f2bf(W[k * 256 + n]);
}

// ---------------- GEMM: h1'[row][col] = dinv[row] * (x @ B), row-major ----------------
// A is read as f32 and cast to bf16 during LDS staging (castX fused; pad rows = 0).
__global__ __launch_bounds__(256) void k_gemm(const float* __restrict__ x,
                                              const unsigned short* __restrict__ Bt,
                                              const float* __restrict__ dinv,
                                              unsigned short* __restrict__ C) {
  __shared__ unsigned short As[128][40];
  __shared__ unsigned short Bs[64][40];
  int tid = threadIdx.x;
  int lane = tid & 63;
  int wave = tid >> 6;
  int wm = wave >> 1, wn = wave & 1;
  int m0 = blockIdx.x * 128, n0 = blockIdx.y * 64;
  int l15 = lane & 15, l4 = lane >> 4;
  f32x4 acc[4][2] = {};

  for (int ks = 0; ks < 8; ++ks) {
    int k0 = ks * 32;
    {
#pragma unroll
      for (int h = 0; h < 2; ++h) {
        int c = tid + h * 256, r = c >> 2, cc = c & 3;
        int row = m0 + r;
        uint4 u = make_uint4(0u, 0u, 0u, 0u);
        if (row < NN) {
          const float4* xp = (const float4*)(x + (size_t)row * 256 + k0 + cc * 8);
          float4 f0 = xp[0], f1 = xp[1];
          u.x = (unsigned int)f2bf(f0.x) | ((unsigned int)f2bf(f0.y) << 16);
          u.y = (unsigned int)f2bf(f0.z) | ((unsigned int)f2bf(f0.w) << 16);
          u.z = (unsigned int)f2bf(f1.x) | ((unsigned int)f2bf(f1.y) << 16);
          u.w = (unsigned int)f2bf(f1.z) | ((unsigned int)f2bf(f1.w) << 16);
        }
        *(uint4*)(&As[r][cc * 8]) = u;
      }
      int c = tid, r = c >> 2, cc = c & 3;
      *(uint4*)(&Bs[r][cc * 8]) = *(const uint4*)(Bt + (size_t)(n0 + r) * 256 + k0 + cc * 8);
    }
    __syncthreads();
    bf16x8 a[4], b[2];
#pragma unroll
    for (int fm = 0; fm < 4; ++fm)
      a[fm] = *(const bf16x8*)(&As[wm * 64 + fm * 16 + l15][l4 * 8]);
#pragma unroll
    for (int fn = 0; fn < 2; ++fn)
      b[fn] = *(const bf16x8*)(&Bs[wn * 32 + fn * 16 + l15][l4 * 8]);
#pragma unroll
    for (int fm = 0; fm < 4; ++fm)
#pragma unroll
      for (int fn = 0; fn < 2; ++fn)
        acc[fm][fn] = __builtin_amdgcn_mfma_f32_16x16x32_bf16(a[fm], b[fn], acc[fm][fn], 0, 0, 0);
    __syncthreads();
  }
  int r0 = l4 * 4;
#pragma unroll
  for (int fm = 0; fm < 4; ++fm)
#pragma unroll
    for (int fn = 0; fn < 2; ++fn) {
      int row = m0 + wm * 64 + fm * 16 + r0;
      int col = n0 + wn * 32 + fn * 16 + l15;
#pragma unroll
      for (int r = 0; r < 4; ++r) {
        int rr = row + r;
        float dv = dinv[rr < NN ? rr : 0];
        C[(size_t)rr * 256 + col] = f2bf(dv * acc[fm][fn][r]);
      }
    }
}

// ---------------- counting sort (by dst) ----------------
__global__ __launch_bounds__(256) void k_hist2(const int* __restrict__ key,
                                               unsigned int* __restrict__ partial) {
  __shared__ unsigned int lh[HBINS / 2];  // 64 KB u16-packed
  int tid = threadIdx.x;
  int c = blockIdx.x, p = blockIdx.y;
  for (int w = tid; w < HBINS / 2; w += 256) lh[w] = 0u;
  __syncthreads();
  int lo = c * EPC, hi = lo + EPC;
  int b0 = p * HBINS;
  for (int i = lo + tid; i < hi; i += 256) {
    int rel = key[i] - b0;
    if ((unsigned)rel < (unsigned)HBINS)
      atomicAdd(&lh[rel >> 1], 1u << ((rel & 1) * 16));
  }
  __syncthreads();
  int wbase = p * (HBINS / 2);
  for (int w = tid; w < HBINS / 2; w += 256) {
    int gw = wbase + w;
    if (gw < NN / 2) partial[(size_t)c * (NN / 2) + gw] = lh[w];
  }
}

// reduce partials -> deg, dinv AND per-256-node block sums (fused k_reduce + k_bsum)
__global__ __launch_bounds__(128) void k_redb(const unsigned int* __restrict__ partial,
                                              int* __restrict__ deg,
                                              float* __restrict__ dinv,
                                              int* __restrict__ bsums) {
  __shared__ int s[128];
  int b = blockIdx.x, t = threadIdx.x;
  int w = b * 128 + t;
  unsigned int sl = 0, sh = 0;
  if (w < NN / 2) {
#pragma unroll
    for (int c = 0; c < HC; ++c) {
      unsigned int v = partial[(size_t)c * (NN / 2) + w];
      sl += v & 0xffffu;
      sh += v >> 16;
    }
    *(int2*)(deg + 2 * w) = make_int2((int)sl, (int)sh);
    dinv[2 * w] = rsqrtf((float)sl + 1.0f);
    dinv[2 * w + 1] = rsqrtf((float)sh + 1.0f);
  }
  s[t] = (int)(sl + sh);
  __syncthreads();
  for (int off = 64; off > 0; off >>= 1) {
    if (t < off) s[t] += s[t + off];
    __syncthreads();
  }
  if (t == 0) bsums[b] = s[0];
}

__global__ __launch_bounds__(256) void k_sscan(int* __restrict__ bsums) {
  __shared__ int s[256];
  int t = threadIdx.x;
  int v = (t < SB) ? bsums[t] : 0;
  s[t] = v; __syncthreads();
  for (int off = 1; off < 256; off <<= 1) {
    int tmp = (t >= off) ? s[t - off] : 0;
    __syncthreads();
    s[t] += tmp;
    __syncthreads();
  }
  if (t < SB) bsums[t] = s[t] - v;  // exclusive
}
__global__ __launch_bounds__(256) void k_fillrp(const int* __restrict__ deg,
                                                const int* __restrict__ bsums,
                                                int* __restrict__ rp) {
  __shared__ int s[256];
  int b = blockIdx.x, t = threadIdx.x, i = b * 256 + t;
  int v = (i < NN) ? deg[i] : 0;
  s[t] = v; __syncthreads();
  for (int off = 1; off < 256; off <<= 1) {
    int tmp = (t >= off) ? s[t - off] : 0;
    __syncthreads();
    s[t] += tmp;
    __syncthreads();
  }
  int excl = bsums[b] + s[t] - v;
  if (i <= NN) rp[i] = excl;
}

// base[c][b] = rp[b] + sum_{c'<c} partial16[c'][b]
__global__ void k_base(const unsigned short* __restrict__ partial16,
                       const int* __restrict__ rp, int* __restrict__ base) {
  int b = blockIdx.x * blockDim.x + threadIdx.x;
  if (b >= NN) return;
  int run = rp[b];
#pragma unroll
  for (int c = 0; c < HC; ++c) {
    base[(size_t)c * NN + b] = run;
    run += (int)partial16[(size_t)c * NN + b];
  }
}

// graph boundaries from sorted batch
__global__ void k_bounds(const int* __restrict__ batch, int* __restrict__ starts) {
  int i = blockIdx.x * blockDim.x + threadIdx.x;
  if (i > NN) return;
  if (i == 0) {
    int b0 = batch[0];
    for (int g = 0; g <= b0; ++g) starts[g] = 0;
  } else if (i == NN) {
    int bl = batch[NN - 1];
    for (int g = bl + 1; g <= NG; ++g) starts[g] = NN;
  } else {
    int a = batch[i - 1], b = batch[i];
    for (int g = a + 1; g <= b; ++g) starts[g] = i;
  }
}

// in-CSR fill (keyed by dst): csr_pk = ((dst&127)<<25) | (src<<9)
__global__ __launch_bounds__(256) void k_fill2(const int* __restrict__ src,
                                               const int* __restrict__ dst,
                                               const int* __restrict__ base,
                                               unsigned int* __restrict__ csr_pk) {
  __shared__ unsigned int pos[FBINS];  // 64 KB
  int tid = threadIdx.x;
  int c = blockIdx.x, p = blockIdx.y;
  int b0 = p * FBINS;
  for (int w = tid; w < FBINS; w += 256) {
    int gb = b0 + w;
    pos[w] = (gb < NN) ? (unsigned int)base[(size_t)c * NN + gb] : 0u;
  }
  __syncthreads();
  int lo = c * EPC, hi = lo + EPC;
  for (int i = lo + tid; i < hi; i += 256) {
    int d = dst[i];
    int s = src[i];
    int rel = d - b0;
    if ((unsigned)rel < (unsigned)FBINS) {
      int idx = (int)atomicAdd(&pos[rel], 1u);
      csr_pk[idx] = ((unsigned int)(d & (TN - 1)) << 25) | ((unsigned int)s << 9);
    }
  }
}

// ---------------- conv1: wave-per-CH-dsts, full 256-feature row per edge ----------------
__global__ __launch_bounds__(256) void k_agg1w(const unsigned short* __restrict__ h1,
                                               const unsigned int* __restrict__ csr_pk,
                                               const int* __restrict__ rp,
                                               const float* __restrict__ dinv,
                                               const float* __restrict__ b1,
                                               unsigned short* __restrict__ z) {
  int wid = blockIdx.x * 4 + (threadIdx.x >> 6);
  int lane = threadIdx.x & 63;
  int d0 = wid * CH;
  if (d0 >= NN) return;
  float4 b1v = *(const float4*)(b1 + lane * 4);
  int e0 = rp[d0], e1 = rp[d0 + CH];
  int base_d = d0 - (d0 & (TN - 1));
  const char* h1b = (const char*)h1;
  int lane8 = lane * 8;
  float a0 = 0.f, a1 = 0.f, a2 = 0.f, a3 = 0.f;
  int cur = -1;
  unsigned int wmask = 0u;

  auto flushz = [&](int rel) {
    int d = base_d + rel;
    wmask |= 1u << (d - d0);
    float di = dinv[d];
    uint2 hv = *(const uint2*)(h1b + ((size_t)d << 9) + lane8);
    float u0 = di * (a0 + bflo(hv.x)) + b1v.x;
    float u1 = di * (a1 + bfhi(hv.x)) + b1v.y;
    float u2 = di * (a2 + bflo(hv.y)) + b1v.z;
    float u3 = di * (a3 + bfhi(hv.y)) + b1v.w;
    u0 = u0 > 0.f ? u0 : expm1f(u0);
    u1 = u1 > 0.f ? u1 : expm1f(u1);
    u2 = u2 > 0.f ? u2 : expm1f(u2);
    u3 = u3 > 0.f ? u3 : expm1f(u3);
    uint2 ow;
    ow.x = (unsigned int)f2bf(di * u0) | ((unsigned int)f2bf(di * u1) << 16);
    ow.y = (unsigned int)f2bf(di * u2) | ((unsigned int)f2bf(di * u3) << 16);
    *(uint2*)((char*)z + ((size_t)d << 9) + lane8) = ow;
    a0 = a1 = a2 = a3 = 0.f;
  };

  unsigned int pk = 0u;
  if (e0 + lane < e1) pk = csr_pk[e0 + lane];
  for (int bb = e0; bb < e1; bb += 64) {
    int n = min(64, e1 - bb);
    unsigned int npk = 0u;
    if (bb + 64 + lane < e1) npk = csr_pk[bb + 64 + lane];
    for (int q = 0; q < n; q += 16) {
      int m = n - q; m = m > 16 ? 16 : m;
      unsigned int p[16]; uint2 vv[16];
      if (m == 16) {
#pragma unroll
        for (int t = 0; t < 16; ++t) p[t] = (unsigned int)__shfl((int)pk, q + t, 64);
#pragma unroll
        for (int t = 0; t < 16; ++t)
          vv[t] = *(const uint2*)(h1b + (p[t] & 0x1FFFFFFu) + lane8);
#pragma unroll
        for (int t = 0; t < 16; ++t) {
          int rel = (int)(p[t] >> 25);
          if (rel != cur) { if (cur >= 0) flushz(cur); cur = rel; }
          a0 += bflo(vv[t].x); a1 += bfhi(vv[t].x);
          a2 += bflo(vv[t].y); a3 += bfhi(vv[t].y);
        }
      } else {
#pragma unroll
        for (int t = 0; t < 16; ++t) if (t < m)
          p[t] = (unsigned int)__shfl((int)pk, q + t, 64);
#pragma unroll
        for (int t = 0; t < 16; ++t) if (t < m)
          vv[t] = *(const uint2*)(h1b + (p[t] & 0x1FFFFFFu) + lane8);
#pragma unroll
        for (int t = 0; t < 16; ++t) if (t < m) {
          int rel = (int)(p[t] >> 25);
          if (rel != cur) { if (cur >= 0) flushz(cur); cur = rel; }
          a0 += bflo(vv[t].x); a1 += bfhi(vv[t].x);
          a2 += bflo(vv[t].y); a3 += bfhi(vv[t].y);
        }
      }
    }
    pk = npk;
  }
  if (cur >= 0) flushz(cur);
#pragma unroll
  for (int j = 0; j < CH; ++j)
    if (!((wmask >> j) & 1u)) flushz((d0 & (TN - 1)) + j);
}

// ---------------- conv2+pool: same skeleton over z'; per-graph reg acc -> atomic pool ----
__global__ __launch_bounds__(256) void k_agg2w(const unsigned short* __restrict__ zz,
                                               const unsigned int* __restrict__ csr_pk,
                                               const int* __restrict__ rp,
                                               const float* __restrict__ dinv,
                                               const int* __restrict__ batch,
                                               float* __restrict__ pool) {
  int wid = blockIdx.x * 4 + (threadIdx.x >> 6);
  int lane = threadIdx.x & 63;
  int d0 = wid * CH;
  if (d0 >= NN) return;
  int e0 = rp[d0], e1 = rp[d0 + CH];
  int base_d = d0 - (d0 & (TN - 1));
  const char* zb8 = (const char*)zz;
  int lane8 = lane * 8;
  float a0 = 0.f, a1 = 0.f, a2 = 0.f, a3 = 0.f;
  float rg0 = 0.f, rg1 = 0.f, rg2 = 0.f, rg3 = 0.f;
  int cur = -1, curg = -1;
  unsigned int wmask = 0u;

  auto gflush = [&]() {
    if (curg >= 0) {
      float* pp = pool + curg * 256 + lane * 4;
      atomicAdd(pp + 0, rg0); atomicAdd(pp + 1, rg1);
      atomicAdd(pp + 2, rg2); atomicAdd(pp + 3, rg3);
      rg0 = rg1 = rg2 = rg3 = 0.f;
    }
  };
  auto dflush = [&](int rel) {
    int d = base_d + rel;
    wmask |= 1u << (d - d0);
    float di = dinv[d];
    uint2 zv = *(const uint2*)(zb8 + ((size_t)d << 9) + lane8);
    int g = batch[d];
    if (g != curg) { gflush(); curg = g; }
    rg0 += di * (a0 + bflo(zv.x)); rg1 += di * (a1 + bfhi(zv.x));
    rg2 += di * (a2 + bflo(zv.y)); rg3 += di * (a3 + bfhi(zv.y));
    a0 = a1 = a2 = a3 = 0.f;
  };

  unsigned int pk = 0u;
  if (e0 + lane < e1) pk = csr_pk[e0 + lane];
  for (int bb = e0; bb < e1; bb += 64) {
    int n = min(64, e1 - bb);
    unsigned int npk = 0u;
    if (bb + 64 + lane < e1) npk = csr_pk[bb + 64 + lane];
    for (int q = 0; q < n; q += 16) {
      int m = n - q; m = m > 16 ? 16 : m;
      unsigned int p[16]; uint2 vv[16];
      if (m == 16) {
#pragma unroll
        for (int t = 0; t < 16; ++t) p[t] = (unsigned int)__shfl((int)pk, q + t, 64);
#pragma unroll
        for (int t = 0; t < 16; ++t)
          vv[t] = *(const uint2*)(zb8 + (p[t] & 0x1FFFFFFu) + lane8);
#pragma unroll
        for (int t = 0; t < 16; ++t) {
          int rel = (int)(p[t] >> 25);
          if (rel != cur) { if (cur >= 0) dflush(cur); cur = rel; }
          a0 += bflo(vv[t].x); a1 += bfhi(vv[t].x);
          a2 += bflo(vv[t].y); a3 += bfhi(vv[t].y);
        }
      } else {
#pragma unroll
        for (int t = 0; t < 16; ++t) if (t < m)
          p[t] = (unsigned int)__shfl((int)pk, q + t, 64);
#pragma unroll
        for (int t = 0; t < 16; ++t) if (t < m)
          vv[t] = *(const uint2*)(zb8 + (p[t] & 0x1FFFFFFu) + lane8);
#pragma unroll
        for (int t = 0; t < 16; ++t) if (t < m) {
          int rel = (int)(p[t] >> 25);
          if (rel != cur) { if (cur >= 0) dflush(cur); cur = rel; }
          a0 += bflo(vv[t].x); a1 += bfhi(vv[t].x);
          a2 += bflo(vv[t].y); a3 += bfhi(vv[t].y);
        }
      }
    }
    pk = npk;
  }
  if (cur >= 0) dflush(cur);
#pragma unroll
  for (int j = 0; j < CH; ++j)
    if (!((wmask >> j) & 1u)) dflush((d0 & (TN - 1)) + j);
  gflush();
}

// ---------------- f = (pool/c) @ W2 + b2 ----------------
__global__ __launch_bounds__(256) void k_featF(const float* __restrict__ pool_s,
                                               const float* __restrict__ pool_n,
                                               const int* __restrict__ st_s,
                                               const int* __restrict__ st_n,
                                               const float* __restrict__ W2,
                                               const float* __restrict__ b2,
                                               float* __restrict__ fstate,
                                               float* __restrict__ fnext,
                                               float* __restrict__ out) {
  int g = blockIdx.x, which = blockIdx.y, j = threadIdx.x;
  const float* pool = which ? pool_n : pool_s;
  const int* st = which ? st_n : st_s;
  int c = st[g + 1] - st[g];
  __shared__ float v[256];
  float cc = fmaxf((float)c, 1.0f);
  v[j] = pool[g * 256 + j] / cc;
  __syncthreads();
  float acc = 0.f;
  for (int k = 0; k < 256; ++k) acc += v[k] * W2[k * 256 + j];
  float val = (c > 0) ? (acc + b2[j]) : 0.f;
  if (which) { fnext[g * 256 + j] = val; out[g * 256 + j] = val; }
  else fstate[g * 256 + j] = val;
}

// ---------------- heads ----------------
__global__ __launch_bounds__(256) void k_head(const float* __restrict__ fstate,
                                              const float* __restrict__ fnext,
                                              const int* __restrict__ action,
                                              const float* __restrict__ Wf, const float* __restrict__ bfv,
                                              const float* __restrict__ Wi1, const float* __restrict__ bi1,
                                              const float* __restrict__ Wi2, const float* __restrict__ bi2,
                                              const float* __restrict__ Wi3, const float* __restrict__ bi3,
                                              float* __restrict__ out) {
  int g = blockIdx.x, j = threadIdx.x;
  __shared__ float fs[256], fn_[256], z1[128], z2[128];
  fs[j] = fstate[g * 256 + j];
  fn_[j] = fnext[g * 256 + j];
  __syncthreads();
  int a = action[g];
  float acc = bfv[j] + Wf[a * 256 + j];
  for (int k = 0; k < 256; ++k) acc += fs[k] * Wf[(16 + k) * 256 + j];
  out[16384 + g * 256 + j] = acc;
  if (j < 128) {
    float t = bi1[j];
    for (int k = 0; k < 256; ++k)
      t += fs[k] * Wi1[k * 128 + j] + fn_[k] * Wi1[(256 + k) * 128 + j];
    z1[j] = fmaxf(t, 0.f);
  }
  __syncthreads();
  if (j < 128) {
    float t = bi2[j];
    for (int k = 0; k < 128; ++k) t += z1[k] * Wi2[k * 128 + j];
    z2[j] = fmaxf(t, 0.f);
  }
  __syncthreads();
  if (j < 16) {
    float t = bi3[j];
    for (int k = 0; k < 128; ++k) t += z2[k] * Wi3[k * 16 + j];
    out[32768 + g * 16 + j] = t;
  }
}

// ---------------- workspace layout ----------------
static constexpr size_t AL(size_t x) { return (x + 255) & ~(size_t)255; }
static constexpr size_t O_H1   = 0;                                    // 25.6 MB (sort scratch aliases)
static constexpr size_t O_Z    = O_H1 + AL((size_t)MPAD * DD * 2);     // 25.6 MB row-major z'
static constexpr size_t O_CSRS = O_Z + AL((size_t)NN * DD * 2);
static constexpr size_t O_RP   = O_CSRS + AL((size_t)NE * 4);
static constexpr size_t O_DINV = O_RP + AL((size_t)(NN + 1) * 4);
static constexpr size_t O_DEG  = O_DINV + AL((size_t)NN * 4);
static constexpr size_t O_BS   = O_DEG + AL((size_t)NN * 4);
static constexpr size_t O_ST0  = O_BS + AL(256 * 4);
static constexpr size_t O_ST1  = O_ST0 + AL((NG + 1) * 4);
static constexpr size_t O_WT   = O_ST1 + AL((NG + 1) * 4);
static constexpr size_t O_PS   = O_WT + AL((size_t)DD * DD * 2);
static constexpr size_t O_PN   = O_PS + AL((size_t)NG * DD * 4);
static constexpr size_t O_FS   = O_PN + AL((size_t)NG * DD * 4);
static constexpr size_t O_FN   = O_FS + AL((size_t)NG * DD * 4);
static constexpr size_t O_BASE0 = O_FN + AL((size_t)NG * DD * 4);       // HC*NN u32 = 12.8 MB
static constexpr size_t O_END  = O_BASE0 + AL((size_t)HC * NN * 4);
// aliased scratch (inside h1, used only before k_gemm writes h1):
static constexpr size_t O_PART = O_H1;                                  // HC*NN/2 u32 = 6.4 MB

extern "C" void kernel_launch(void* const* d_in, const int* in_sizes, int n_in,
                              void* d_out, int out_size, void* d_ws, size_t ws_size,
                              hipStream_t stream) {
  const float* x_s     = (const float*)d_in[0];
  const int*   ei_s    = (const int*)d_in[1];
  const int*   batch_s = (const int*)d_in[2];
  const float* x_n     = (const float*)d_in[3];
  const int*   ei_n    = (const int*)d_in[4];
  const int*   batch_n = (const int*)d_in[5];
  const int*   action  = (const int*)d_in[6];
  const float* W1      = (const float*)d_in[7];
  const float* b1      = (const float*)d_in[8];
  const float* W2      = (const float*)d_in[9];
  const float* b2      = (const float*)d_in[10];
  const float* Wf      = (const float*)d_in[11];
  const float* bfv     = (const float*)d_in[12];
  const float* Wi1     = (const float*)d_in[13];
  const float* bi1     = (const float*)d_in[14];
  const float* Wi2     = (const float*)d_in[15];
  const float* bi2     = (const float*)d_in[16];
  const float* Wi3     = (const float*)d_in[17];
  const float* bi3     = (const float*)d_in[18];
  float* out = (float*)d_out;
  char* ws = (char*)d_ws;
  if (ws_size < O_END) return;

  unsigned short* h1  = (unsigned short*)(ws + O_H1);
  unsigned short* zb  = (unsigned short*)(ws + O_Z);
  unsigned int* csr_pk = (unsigned int*)(ws + O_CSRS);
  int*   rp      = (int*)(ws + O_RP);
  float* dinv    = (float*)(ws + O_DINV);
  int*   deg     = (int*)(ws + O_DEG);
  int*   bsums   = (int*)(ws + O_BS);
  unsigned short* Wt = (unsigned short*)(ws + O_WT);
  float* fstate  = (float*)(ws + O_FS);
  float* fnext   = (float*)(ws + O_FN);
  int*   starts[2] = { (int*)(ws + O_ST0), (int*)(ws + O_ST1) };
  float* pool[2]   = { (float*)(ws + O_PS), (float*)(ws + O_PN) };
  unsigned int* partial = (unsigned int*)(ws + O_PART);
  int*          basebuf = (int*)(ws + O_BASE0);

  // zero both pool accumulators (agg2w uses atomics)
  k_zero<<<64, 256, 0, stream>>>((unsigned int*)(ws + O_PS), 2 * NG * DD);
  k_castW<<<(DD * DD) / 256, 256, 0, stream>>>(W1, Wt);

  const float* xs[2]  = { x_s, x_n };
  const int*   eis[2] = { ei_s, ei_n };
  const int*   bts[2] = { batch_s, batch_n };

  for (int gidx = 0; gidx < 2; ++gidx) {
    const float* x = xs[gidx];
    const int* src = eis[gidx];
    const int* dst = eis[gidx] + NE;
    const int* batch = bts[gidx];

    // --- in-CSR (by dst): deg/dinv/bsums, rp, csr_pk ---
    k_hist2<<<dim3(HC, 2), 256, 0, stream>>>(dst, partial);
    k_redb<<<SB, 128, 0, stream>>>(partial, deg, dinv, bsums);
    k_sscan<<<1, 256, 0, stream>>>(bsums);
    k_fillrp<<<SB, 256, 0, stream>>>(deg, bsums, rp);
    k_base<<<(NN + 255) / 256, 256, 0, stream>>>((const unsigned short*)partial, rp, basebuf);
    k_fill2<<<dim3(HC, (NN + FBINS - 1) / FBINS), 256, 0, stream>>>(src, dst, basebuf, csr_pk);
    k_bounds<<<(NN + 1 + 255) / 256, 256, 0, stream>>>(batch, starts[gidx]);

    // --- dense GEMM (castX fused into A-staging; frees sort scratch), then aggregations ---
    k_gemm<<<dim3(MPAD / 128, DD / 64), 256, 0, stream>>>(x, Wt, dinv, h1);
    int nwaves = NN / CH;                      // 6250
    int nblk = (nwaves + 3) / 4;               // 1563
    k_agg1w<<<nblk, 256, 0, stream>>>(h1, csr_pk, rp, dinv, b1, zb);
    k_agg2w<<<nblk, 256, 0, stream>>>(zb, csr_pk, rp, dinv, batch, pool[gidx]);
  }

  k_featF<<<dim3(NG, 2), 256, 0, stream>>>(pool[0], pool[1], starts[0], starts[1], W2, b2,
                                           fstate, fnext, out);
  k_head<<<NG, 256, 0, stream>>>(fstate, fnext, action, Wf, bfv,
                                 Wi1, bi1, Wi2, bi2, Wi3, bi3, out);
}